// Round 7
// baseline (123.102 us; speedup 1.0000x reference)
//
#include <hip/hip_runtime.h>

#define NB 128      // batch
#define NT 4096     // T
#define DKD 16      // d_k == d_q
#define DW 32       // d_w
#define CHUNKS 4    // T chunks: 512 blocks, 2 blocks/CU
#define TC 1024     // NT / CHUNKS
#define BLK 256
#define PT 4        // t-values per thread, processed as a 4-stage pipeline

__device__ __forceinline__ float fast_tanh(float x) {
    // tanh(x) = 1 - 2/(e^{2x}+1); exact at +/-inf limits, ~1 ulp rcp error.
    float e = __expf(2.0f * x);
    return 1.0f - 2.0f * __builtin_amdgcn_rcpf(e + 1.0f);
}

// Rounds 0-6 established: fence-free 2-kernel structure (fences cost 40-60us),
// pair stuck at ~30us regardless of occupancy/PT/DS because every variant
// issued ALL loads in one chip-wide pulse -> ~11us pure-stream phase then
// ~7us pure-compute phase, serialized. This round pipelines WITHIN the
// thread: 4 one-t stages, ping-pong registers, next-next-t loads issued at
// each stage start, sched_barrier(0) between stages so the compiler cannot
// re-hoist the loads back into a single pulse. Memory requests now trickle
// in behind compute -> steady-state overlap, like the 6.3TB/s copy ubench.
// W2 is read wave-uniformly from global (scalar cache, s_load) keeping the
// DS pipe nearly idle; the 16-FMA dot is split into 4 parallel chains so a
// single-t stage is not latency-bound on one serial FMA chain.

// One stage: score(t) from k-regs, p=exp, ctx accumulate from v-regs.
// |score| <= ||v_w||_1 + |v_b| ~ 2.6 (tanh bounded) -> no max-subtract.
#define SCORE_STAGE(K0, K1, K2, K3, X0, X1, X2, X3, POUT)                     \
    do {                                                                      \
        float sc_ = vb;                                                       \
        _Pragma("unroll 8")                                                   \
        for (int w = 0; w < DW; ++w) {                                        \
            const float4* wr_ = reinterpret_cast<const float4*>(W2) + w * 4;  \
            const float4 u0 = wr_[0], u1 = wr_[1], u2 = wr_[2], u3 = wr_[3];  \
            const float2 cv_ = s_cv[w];                                       \
            float h0 = fmaf(K0.x, u0.x, cv_.x);                               \
            h0 = fmaf(K0.y, u0.y, h0); h0 = fmaf(K0.z, u0.z, h0);             \
            h0 = fmaf(K0.w, u0.w, h0);                                        \
            float h1 = K1.x * u1.x;                                           \
            h1 = fmaf(K1.y, u1.y, h1); h1 = fmaf(K1.z, u1.z, h1);             \
            h1 = fmaf(K1.w, u1.w, h1);                                        \
            float h2 = K2.x * u2.x;                                           \
            h2 = fmaf(K2.y, u2.y, h2); h2 = fmaf(K2.z, u2.z, h2);             \
            h2 = fmaf(K2.w, u2.w, h2);                                        \
            float h3 = K3.x * u3.x;                                           \
            h3 = fmaf(K3.y, u3.y, h3); h3 = fmaf(K3.z, u3.z, h3);             \
            h3 = fmaf(K3.w, u3.w, h3);                                        \
            const float h_ = (h0 + h1) + (h2 + h3);                           \
            sc_ = fmaf(fast_tanh(h_), cv_.y, sc_);                            \
        }                                                                     \
        POUT = __expf(sc_);                                                   \
        l += POUT;                                                            \
        ctx[ 0] = fmaf(POUT, X0.x, ctx[ 0]); ctx[ 1] = fmaf(POUT, X0.y, ctx[ 1]); \
        ctx[ 2] = fmaf(POUT, X0.z, ctx[ 2]); ctx[ 3] = fmaf(POUT, X0.w, ctx[ 3]); \
        ctx[ 4] = fmaf(POUT, X1.x, ctx[ 4]); ctx[ 5] = fmaf(POUT, X1.y, ctx[ 5]); \
        ctx[ 6] = fmaf(POUT, X1.z, ctx[ 6]); ctx[ 7] = fmaf(POUT, X1.w, ctx[ 7]); \
        ctx[ 8] = fmaf(POUT, X2.x, ctx[ 8]); ctx[ 9] = fmaf(POUT, X2.y, ctx[ 9]); \
        ctx[10] = fmaf(POUT, X2.z, ctx[10]); ctx[11] = fmaf(POUT, X2.w, ctx[11]); \
        ctx[12] = fmaf(POUT, X3.x, ctx[12]); ctx[13] = fmaf(POUT, X3.y, ctx[13]); \
        ctx[14] = fmaf(POUT, X3.z, ctx[14]); ctx[15] = fmaf(POUT, X3.w, ctx[15]); \
    } while (0)

__global__ __launch_bounds__(BLK, 2) void aa_score(
    const float* __restrict__ query, const float* __restrict__ key,
    const float* __restrict__ value, const float* __restrict__ W1,
    const float* __restrict__ W2, const float* __restrict__ bias,
    const float* __restrict__ v_w, const float* __restrict__ v_b,
    float* __restrict__ attn,      // out + 2048: unnormalized p written here
    float* __restrict__ ws_l,      // [NB*CHUNKS]
    float* __restrict__ ws_ctx)    // [NB*CHUNKS*16]
{
    const int b   = blockIdx.x >> 2;            // blockIdx / CHUNKS
    const int c   = blockIdx.x & (CHUNKS - 1);
    const int tid = threadIdx.x;

    __shared__ float2 s_cv[DW];        // (comb = q_proj + bias, vw) pairs
    __shared__ float s_rctx[4 * 16];   // per-wave partial ctx
    __shared__ float s_rl[4];

    // Preamble: 32 lanes compute q_proj + bias and pack (comb, vw).
    if (tid < DW) {
        float acc = bias[0];
        const float* q  = query + b * DKD;
        const float* wr = W1 + tid * DKD;
        #pragma unroll
        for (int d = 0; d < DKD; ++d) acc = fmaf(q[d], wr[d], acc);
        s_cv[tid] = make_float2(acc, v_w[tid]);
    }
    __syncthreads();

    const float vb = v_b[0];
    const size_t tbase = (size_t)b * NT + (size_t)c * TC + (size_t)tid * PT;
    const float4* kp = reinterpret_cast<const float4*>(key)   + tbase * 4;
    const float4* vp = reinterpret_cast<const float4*>(value) + tbase * 4;

    float l = 0.0f;
    float ctx[16];
    #pragma unroll
    for (int d = 0; d < 16; ++d) ctx[d] = 0.0f;
    float p0, p1, p2, p3;

    // Pipeline prologue: t0 and t1 in flight (2-ahead).
    float4 ka0 = kp[ 0], ka1 = kp[ 1], ka2 = kp[ 2], ka3 = kp[ 3];
    float4 xa0 = vp[ 0], xa1 = vp[ 1], xa2 = vp[ 2], xa3 = vp[ 3];
    float4 kb0 = kp[ 4], kb1 = kp[ 5], kb2 = kp[ 6], kb3 = kp[ 7];
    float4 xb0 = vp[ 4], xb1 = vp[ 5], xb2 = vp[ 6], xb3 = vp[ 7];

    // Stage 0: compute t0; t2's loads issue behind it.
    SCORE_STAGE(ka0, ka1, ka2, ka3, xa0, xa1, xa2, xa3, p0);
    __builtin_amdgcn_sched_barrier(0);
    ka0 = kp[ 8]; ka1 = kp[ 9]; ka2 = kp[10]; ka3 = kp[11];
    xa0 = vp[ 8]; xa1 = vp[ 9]; xa2 = vp[10]; xa3 = vp[11];

    // Stage 1: compute t1; t3's loads issue behind it.
    SCORE_STAGE(kb0, kb1, kb2, kb3, xb0, xb1, xb2, xb3, p1);
    __builtin_amdgcn_sched_barrier(0);
    kb0 = kp[12]; kb1 = kp[13]; kb2 = kp[14]; kb3 = kp[15];
    xb0 = vp[12]; xb1 = vp[13]; xb2 = vp[14]; xb3 = vp[15];

    // Stage 2: compute t2.
    SCORE_STAGE(ka0, ka1, ka2, ka3, xa0, xa1, xa2, xa3, p2);
    __builtin_amdgcn_sched_barrier(0);

    // Stage 3: compute t3.
    SCORE_STAGE(kb0, kb1, kb2, kb3, xb0, xb1, xb2, xb3, p3);

    // Write unnormalized p (kernel 2 normalizes in place): 16 B/lane,
    // wave-contiguous 1 KB — coalesced.
    reinterpret_cast<float4*>(attn + (size_t)b * NT + (size_t)c * TC)[tid] =
        make_float4(p0, p1, p2, p3);

    // Block reduction: wave shuffle-reduce, then 4 waves via LDS.
    #pragma unroll
    for (int o = 32; o > 0; o >>= 1) l += __shfl_xor(l, o);
    #pragma unroll
    for (int d = 0; d < 16; ++d) {
        #pragma unroll
        for (int o = 32; o > 0; o >>= 1) ctx[d] += __shfl_xor(ctx[d], o);
    }
    const int wave = tid >> 6;
    const int lane = tid & 63;
    if (lane == 0) {
        s_rl[wave] = l;
        #pragma unroll
        for (int d = 0; d < 16; ++d) s_rctx[wave * 16 + d] = ctx[d];
    }
    __syncthreads();
    const int slot = b * CHUNKS + c;
    if (tid < 16)
        ws_ctx[slot * 16 + tid] =
            s_rctx[tid] + s_rctx[16 + tid] + s_rctx[32 + tid] + s_rctx[48 + tid];
    if (tid == 0)
        ws_l[slot] = s_rl[0] + s_rl[1] + s_rl[2] + s_rl[3];
}

// Kernel 2: normalize attn in place by 1/L and write context. 512 fat blocks
// (float4/thread); L recomputed per block from 4 broadcast (scalar-cache)
// loads — avoids a third kernel.
__global__ __launch_bounds__(BLK) void aa_finish(
    float* __restrict__ out,          // [0,2048) context, [2048,...) attn
    const float* __restrict__ ws_l,
    const float* __restrict__ ws_ctx)
{
    const int b   = blockIdx.x >> 2;            // 4 blocks per batch
    const int q   = blockIdx.x & 3;             // quarter of the row
    const int tid = threadIdx.x;

    float L = 0.0f;
    #pragma unroll
    for (int i = 0; i < CHUNKS; ++i) L += ws_l[b * CHUNKS + i];
    const float inv = 1.0f / L;

    // 4 blocks x 256 threads x float4 = 4096 floats = one batch row.
    float4* ap = reinterpret_cast<float4*>(out + NB * DKD + (size_t)b * NT) +
                 q * BLK + tid;
    float4 p = *ap;
    p.x *= inv; p.y *= inv; p.z *= inv; p.w *= inv;
    *ap = p;

    if (q == 0 && tid < DKD) {
        const float* wc = ws_ctx + b * CHUNKS * 16;
        float s = 0.0f;
        #pragma unroll
        for (int i = 0; i < CHUNKS; ++i) s += wc[i * 16 + tid];
        out[b * DKD + tid] = s * inv;
    }
}

extern "C" void kernel_launch(void* const* d_in, const int* in_sizes, int n_in,
                              void* d_out, int out_size, void* d_ws, size_t ws_size,
                              hipStream_t stream) {
    const float* query = (const float*)d_in[0];
    const float* key   = (const float*)d_in[1];
    const float* value = (const float*)d_in[2];
    const float* W1    = (const float*)d_in[3];
    const float* W2    = (const float*)d_in[4];
    const float* bias  = (const float*)d_in[5];
    const float* v_w   = (const float*)d_in[6];
    const float* v_b   = (const float*)d_in[7];
    float* out = (float*)d_out;

    float* ws_l   = (float*)d_ws;          // NB*CHUNKS floats
    float* ws_ctx = ws_l + NB * CHUNKS;    // NB*CHUNKS*16 floats

    aa_score<<<NB * CHUNKS, BLK, 0, stream>>>(
        query, key, value, W1, W2, bias, v_w, v_b,
        out + NB * DKD, ws_l, ws_ctx);
    aa_finish<<<NB * (NT / 4 / BLK), BLK, 0, stream>>>(out, ws_l, ws_ctx);
}